// Round 6
// baseline (333.533 us; speedup 1.0000x reference)
//
#include <hip/hip_runtime.h>
#include <stdint.h>

// Problem: B=4, T=2048, D_IN=512, D_OUT=512, N_FILT=24.
// Inputs fp32 (runtime-detected, bf16 fallback). Output fp32.
// out[b,t,o] = sum_n phi[t,n] * cumsum_t( phi[t,n] * (M[n] @ x[b,t,:]) )[o]
#define BQ 4
#define TT 2048
#define DF 512
#define DOUT 512
#define NF 24
#define CHF 8   // fast-path scan chunk (rows)

typedef __attribute__((ext_vector_type(8))) short short8;
typedef __attribute__((ext_vector_type(4))) float f32x4;

typedef __attribute__((address_space(3))) uint8_t       lds_u8;
typedef __attribute__((address_space(1))) const uint8_t glb_u8;

__device__ __forceinline__ float bf2f(unsigned short u) {
    union { unsigned int i; float f; } v; v.i = ((unsigned int)u) << 16; return v.f;
}
__device__ __forceinline__ unsigned short f2bf(float f) {
    union { float f; unsigned int i; } v; v.f = f;
    unsigned int r = v.i + 0x7FFFu + ((v.i >> 16) & 1u);  // RNE
    return (unsigned short)(r >> 16);
}
__device__ __forceinline__ float lo16f(unsigned int u) { return __uint_as_float(u << 16); }
__device__ __forceinline__ float hi16f(unsigned int u) { return __uint_as_float(u & 0xffff0000u); }

// ---------------------------------------------------------------------------
// Dtype sniffer (flag=1 => fp32 inputs).
// ---------------------------------------------------------------------------
__device__ __forceinline__ int plaus16(unsigned int h) {
    unsigned int e = (h >> 7) & 0xffu;
    return (e >= 97u && e <= 141u) || ((h & 0x7fffu) == 0u);
}

__global__ void k_detect(const unsigned int* __restrict__ X, int* __restrict__ flag)
{
    const int lane = threadIdx.x;  // 64 threads, 1 block
    int cnt = 0;
#pragma unroll
    for (int i = 0; i < 4; ++i) {
        unsigned int w = X[lane * 4 + i];
        cnt += (plaus16(w >> 16) && plaus16(w & 0xffffu)) ? 1 : 0;
    }
    for (int off = 32; off > 0; off >>= 1) cnt += __shfl_down(cnt, off);
    if (lane == 0) *flag = (cnt < 180) ? 1 : 0;
}

__global__ __launch_bounds__(256) void k_convf(
    const void* __restrict__ src, float* __restrict__ dst,
    const int* __restrict__ flag, int n)
{
    const int isf32 = *flag;
    int i = blockIdx.x * 256 + threadIdx.x;
    const int stride = gridDim.x * 256;
    for (; i < n; i += stride)
        dst[i] = isf32 ? ((const float*)src)[i]
                       : bf2f(((const unsigned short*)src)[i]);
}

// ---------------------------------------------------------------------------
// r16: ONE prep kernel replacing detect + convf + convertX + convertM.
// Residual-time analysis shows ~13 us/launch of dispatch gap (kernel-sum
// ~200 us vs 329 measured across 10 launches; same ratio at r0's 16
// launches) — launch count is a first-order cost. Each block self-computes
// the dtype flag from X's first 1KB (wave-0 shfl reduce; deterministic,
// L2-broadcast) so there is no cross-kernel flag dependency.
// Work = grid-stride over [X uint4-conv | M uint4-conv | F float4-widen].
// ---------------------------------------------------------------------------
__global__ __launch_bounds__(256) void k_prep(
    const void* __restrict__ X, const void* __restrict__ Mw,
    const void* __restrict__ Fil,
    unsigned short* __restrict__ Xbf, unsigned short* __restrict__ Mbf,
    float* __restrict__ Fw, int n4x, int n4m, int n4f)
{
    __shared__ int sflag;
    const int tid = threadIdx.x;
    if (tid < 64) {
        int cnt = 0;
        const unsigned int* Xu = (const unsigned int*)X;
#pragma unroll
        for (int i = 0; i < 4; ++i) {
            unsigned int wd = Xu[tid * 4 + i];
            cnt += (plaus16(wd >> 16) && plaus16(wd & 0xffffu)) ? 1 : 0;
        }
        for (int off = 32; off > 0; off >>= 1) cnt += __shfl_down(cnt, off);
        if (tid == 0) sflag = (cnt < 180) ? 1 : 0;
    }
    __syncthreads();
    const int isf32 = sflag;

    const int total = n4x + n4m + n4f;
    for (int i = blockIdx.x * 256 + tid; i < total; i += gridDim.x * 256) {
        if (i < n4x) {
            ushort4 o;
            if (isf32) {
                float4 v = ((const float4*)X)[i];
                o.x = f2bf(v.x); o.y = f2bf(v.y); o.z = f2bf(v.z); o.w = f2bf(v.w);
            } else {
                o = ((const ushort4*)X)[i];
            }
            ((ushort4*)Xbf)[i] = o;
        } else if (i < n4x + n4m) {
            const int j = i - n4x;
            ushort4 o;
            if (isf32) {
                float4 v = ((const float4*)Mw)[j];
                o.x = f2bf(v.x); o.y = f2bf(v.y); o.z = f2bf(v.z); o.w = f2bf(v.w);
            } else {
                o = ((const ushort4*)Mw)[j];
            }
            ((ushort4*)Mbf)[j] = o;
        } else {
            const int j = i - n4x - n4m;
            if (isf32) {
                ((float4*)Fw)[j] = ((const float4*)Fil)[j];
            } else {
                ushort4 u = ((const ushort4*)Fil)[j];
                ((float4*)Fw)[j] = make_float4(bf2f(u.x), bf2f(u.y),
                                               bf2f(u.z), bf2f(u.w));
            }
        }
    }
}

// ---------------------------------------------------------------------------
// FAST GEMM, fused chunk-sums. m97 pattern + XOR bank swizzle (r10) +
// r12 2-phase dbuf (best of r11/r12/r14 — pipelining beyond this was NULL,
// we sit at the known 2-phase structural ceiling ~690 TF).
// r16: XCD-contiguous work swizzle (T1). Linear block id lid round-robins
// XCDs, so remap work = (lid%8)*(nwg/8) + lid/8: each XCD owns a
// CONTIGUOUS swz range -> each M panel (128KB) is fetched into exactly one
// XCD's L2, and the pass's whole X tile-set (4MB) fits one XCD L2.
// Bijective when nwg%8==0 (G-tier 3072, per-batch 1536); identity else.
// grid (rows/128, 4, NF), block 256.
// ---------------------------------------------------------------------------
__global__ __launch_bounds__(256, 3) void k_gemm_fast(
    const unsigned short* __restrict__ X,   // bf16 [B*T, DF]
    const unsigned short* __restrict__ Mw,  // bf16 [NF][DOUT][DF]
    const float* __restrict__ Fw,           // fp32 [TT][NF]
    unsigned short* __restrict__ Z,         // bf16 [rl][n][512]
    float* __restrict__ Cs,                 // fp32 [chunk][n][512]
    int r0)
{
    // union: dbuf {buf0: A[4096] B[4096] | buf1: A B} (16384 shorts) / sC (17408)
    __shared__ unsigned short sAB[128 * 136];
    __shared__ float sPhi[128];
    unsigned short* const sC = sAB;

    const int tid  = threadIdx.x;
    const int lane = tid & 63;
    const int w    = tid >> 6;
    const int wm   = w & 1, wn = w >> 1;

    // XCD-contiguous swizzle (T1)
    const int gx = gridDim.x, gy = gridDim.y;
    const int nwg = gx * gy * gridDim.z;
    int lid = blockIdx.x + gx * (blockIdx.y + gy * blockIdx.z);
    int swz = lid;
    if ((nwg & 7) == 0) swz = (lid & 7) * (nwg >> 3) + (lid >> 3);
    const int tm   = swz % gx;
    const int rest = swz / gx;
    const int on0  = (rest % gy) * 128;
    const int n    = rest / gy;

    const int rowg0 = r0 + tm * 128;
    if (tid < 128)
        sPhi[tid] = Fw[((rowg0 + tid) & (TT - 1)) * NF + n];

    const unsigned short* Ag = X + (size_t)rowg0 * DF;
    const unsigned short* Bg = Mw + (size_t)n * DOUT * DF + (size_t)on0 * DF;

    // Per-thread staging geometry (16B slots; XOR bank swizzle on source)
    auto stage = [&](int kt, int buf) {
        const unsigned short* Ak = Ag + kt * 32;
        const unsigned short* Bk = Bg + kt * 32;
        lds_u8* base = (lds_u8*)sAB + buf * 16384;
#pragma unroll
        for (int i = 0; i < 2; ++i) {
            const int cbase = i * 256 + w * 64;   // wave-uniform 16B-slot base
            const int c = cbase + lane;           // this lane's LDS slot
            const int r = c >> 2, qs = c & 3;
            const int qg = qs ^ ((r >> 1) & 3);   // swizzle: slot qs holds chunk qg
            __builtin_amdgcn_global_load_lds(
                (const glb_u8*)(Ak + (size_t)r * DF + qg * 8),
                base + cbase * 16, 16, 0, 0);
            __builtin_amdgcn_global_load_lds(
                (const glb_u8*)(Bk + (size_t)r * DF + qg * 8),
                base + 8192 + cbase * 16, 16, 0, 0);
        }
    };

    f32x4 acc[4][4];
#pragma unroll
    for (int i = 0; i < 4; i++)
#pragma unroll
        for (int j = 0; j < 4; j++) acc[i][j] = (f32x4){0.f, 0.f, 0.f, 0.f};

    stage(0, 0);
    __syncthreads();   // vmcnt(0) drain: buf0 ready

    const int lr = lane & 15;
    const int q  = lane >> 4;
    const int qsw = (q ^ ((lr >> 1) & 3)) * 8;    // (row>>1)&3 == (lr>>1)&3

    for (int kt = 0; kt < DF / 32; ++kt) {
        const int cur = kt & 1;
        if (kt < DF / 32 - 1) stage(kt + 1, cur ^ 1);   // loads in flight over compute

        const unsigned short* sAc = sAB + cur * 8192;
        const unsigned short* sBc = sAc + 4096;
        short8 a[4], b[4];
#pragma unroll
        for (int i = 0; i < 4; i++)
            a[i] = *(const short8*)&sAc[(wm * 64 + i * 16 + lr) * 32 + qsw];
#pragma unroll
        for (int j = 0; j < 4; j++)
            b[j] = *(const short8*)&sBc[(wn * 64 + j * 16 + lr) * 32 + qsw];
#pragma unroll
        for (int i = 0; i < 4; i++)
#pragma unroll
            for (int j = 0; j < 4; j++)
                acc[i][j] = __builtin_amdgcn_mfma_f32_16x16x32_bf16(
                    a[i], b[j], acc[i][j], 0, 0, 0);

        __syncthreads();   // drains this iter's stage + guards buf reuse
    }
    // last loop barrier passed: all ds_reads complete, sC may overlay dbuf

    // C/D layout (m89/m91-verified): col = lane&15, row = (lane>>4)*4 + reg
    const int rb = (lane >> 4) * 4;
#pragma unroll
    for (int i = 0; i < 4; i++)
#pragma unroll
        for (int j = 0; j < 4; j++)
#pragma unroll
            for (int r = 0; r < 4; r++) {
                int row = wm * 64 + i * 16 + rb + r;
                sC[row * 136 + wn * 64 + j * 16 + (lane & 15)] =
                    f2bf(acc[i][j][r] * sPhi[row]);
            }
    __syncthreads();

    // Z store (coalesced 16B)
#pragma unroll
    for (int it = 0; it < 8; ++it) {
        int row = it * 16 + (tid >> 4);
        int col = (tid & 15) * 8;
        uint4 v = *(const uint4*)&sC[row * 136 + col];
        *(uint4*)&Z[((size_t)(tm * 128 + row) * NF + n) * 512 + on0 + col] = v;
    }

    // Fused chunk sums: 16 chunks x 128 cols; thread -> (chunk ci, 8 cols).
    {
        const int ci  = tid >> 4;           // chunk within tile, 0..15
        const int col = (tid & 15) * 8;
        float s0=0.f,s1=0.f,s2=0.f,s3=0.f,s4=0.f,s5=0.f,s6=0.f,s7=0.f;
#pragma unroll
        for (int r = 0; r < CHF; ++r) {
            uint4 v = *(const uint4*)&sC[(ci * CHF + r) * 136 + col];
            s0 += lo16f(v.x); s1 += hi16f(v.x);
            s2 += lo16f(v.y); s3 += hi16f(v.y);
            s4 += lo16f(v.z); s5 += hi16f(v.z);
            s6 += lo16f(v.w); s7 += hi16f(v.w);
        }
        float* cp = &Cs[((size_t)(tm * 16 + ci) * NF + n) * 512 + on0 + col];
        *(float4*)cp       = make_float4(s0, s1, s2, s3);
        *(float4*)(cp + 4) = make_float4(s4, s5, s6, s7);
    }
}

// ---------------------------------------------------------------------------
// SLOW GEMM (fallback for tiny ws): register staging + in-flight convert.
// ---------------------------------------------------------------------------
__global__ __launch_bounds__(256, 2) void k_gemm(
    const void* __restrict__ Xv, const void* __restrict__ Mv,
    const void* __restrict__ Fv, const int* __restrict__ flag,
    unsigned short* __restrict__ Z, int r0, int o0, int W)
{
    __shared__ unsigned short sA[128 * 32];
    __shared__ unsigned short sB[128 * 32];
    __shared__ unsigned short sC[128 * 136];
    __shared__ float sPhi[128];

    const int isf32 = *flag;
    const int tid  = threadIdx.x;
    const int lane = tid & 63;
    const int w    = tid >> 6;
    const int wm   = w & 1, wn = w >> 1;
    const int tm   = blockIdx.x;
    const int on0  = o0 + blockIdx.y * 128;
    const int n    = blockIdx.z;

    const int rowg0 = r0 + tm * 128;
    if (tid < 128) {
        int t = (rowg0 + tid) & (TT - 1);
        sPhi[tid] = isf32 ? ((const float*)Fv)[t * NF + n]
                          : bf2f(((const unsigned short*)Fv)[t * NF + n]);
    }

    const unsigned short* Ah = (const unsigned short*)Xv + (size_t)rowg0 * DF;
    const unsigned short* Bh = (const unsigned short*)Mv +
        (size_t)n * DOUT * DF + (size_t)on0 * DF;
    const float* Af = (const float*)Xv + (size_t)rowg0 * DF;
    const float* Bf = (const float*)Mv + (size_t)n * DOUT * DF + (size_t)on0 * DF;

    f32x4 acc[4][4];
#pragma unroll
    for (int i = 0; i < 4; i++)
#pragma unroll
        for (int j = 0; j < 4; j++) acc[i][j] = (f32x4){0.f, 0.f, 0.f, 0.f};

    for (int kt = 0; kt < DF / 32; ++kt) {
        __syncthreads();
        if (!isf32) {
            const unsigned short* Ak = Ah + kt * 32;
            const unsigned short* Bk = Bh + kt * 32;
#pragma unroll
            for (int i = 0; i < 2; ++i) {
                const int c = i * 256 + tid;
                const int r = c >> 2, cc = (c & 3) * 8;
                *(short8*)&sA[r * 32 + cc] = *(const short8*)(Ak + (size_t)r * DF + cc);
                *(short8*)&sB[r * 32 + cc] = *(const short8*)(Bk + (size_t)r * DF + cc);
            }
        } else {
            const float* Ak = Af + kt * 32;
            const float* Bk = Bf + kt * 32;
#pragma unroll
            for (int i = 0; i < 2; ++i) {
                const int c = i * 256 + tid;
                const int r = c >> 2, cc = (c & 3) * 8;
                float4 a0 = *(const float4*)(Ak + (size_t)r * DF + cc);
                float4 a1 = *(const float4*)(Ak + (size_t)r * DF + cc + 4);
                float4 b0 = *(const float4*)(Bk + (size_t)r * DF + cc);
                float4 b1 = *(const float4*)(Bk + (size_t)r * DF + cc + 4);
                short8 sa, sb;
                sa[0]=(short)f2bf(a0.x); sa[1]=(short)f2bf(a0.y);
                sa[2]=(short)f2bf(a0.z); sa[3]=(short)f2bf(a0.w);
                sa[4]=(short)f2bf(a1.x); sa[5]=(short)f2bf(a1.y);
                sa[6]=(short)f2bf(a1.z); sa[7]=(short)f2bf(a1.w);
                sb[0]=(short)f2bf(b0.x); sb[1]=(short)f2bf(b0.y);
                sb[2]=(short)f2bf(b0.z); sb[3]=(short)f2bf(b0.w);
                sb[4]=(short)f2bf(b1.x); sb[5]=(short)f2bf(b1.y);
                sb[6]=(short)f2bf(b1.z); sb[7]=(short)f2bf(b1.w);
                *(short8*)&sA[r * 32 + cc] = sa;
                *(short8*)&sB[r * 32 + cc] = sb;
            }
        }
        __syncthreads();

        const int lr = lane & 15;
        const int lk = (lane >> 4) * 8;
        short8 a[4], b[4];
#pragma unroll
        for (int i = 0; i < 4; i++)
            a[i] = *(const short8*)&sA[(wm * 64 + i * 16 + lr) * 32 + lk];
#pragma unroll
        for (int j = 0; j < 4; j++)
            b[j] = *(const short8*)&sB[(wn * 64 + j * 16 + lr) * 32 + lk];
#pragma unroll
        for (int i = 0; i < 4; i++)
#pragma unroll
            for (int j = 0; j < 4; j++)
                acc[i][j] = __builtin_amdgcn_mfma_f32_16x16x32_bf16(
                    a[i], b[j], acc[i][j], 0, 0, 0);
    }

    const int rb = (lane >> 4) * 4;
#pragma unroll
    for (int i = 0; i < 4; i++)
#pragma unroll
        for (int j = 0; j < 4; j++)
#pragma unroll
            for (int r = 0; r < 4; r++) {
                int row = wm * 64 + i * 16 + rb + r;
                sC[row * 136 + wn * 64 + j * 16 + (lane & 15)] =
                    f2bf(acc[i][j][r] * sPhi[row]);
            }
    __syncthreads();
#pragma unroll
    for (int it = 0; it < 8; ++it) {
        int row = it * 16 + (tid >> 4);
        int col = (tid & 15) * 8;
        uint4 v = *(const uint4*)&sC[row * 136 + col];
        *(uint4*)&Z[((size_t)(tm * 128 + row) * NF + n) * W + (on0 - o0) + col] = v;
    }
}

// ---------------------------------------------------------------------------
// Kernel 2a (slow tier only): chunk sums. grid (nch, NF), block W/2.
// ---------------------------------------------------------------------------
__global__ __launch_bounds__(256, 2) void k_csum(
    const unsigned short* __restrict__ Z, float* __restrict__ Cs,
    int W, int CHs)
{
    const int c = blockIdx.x, n = blockIdx.y, tid = threadIdx.x;
    const unsigned short* p = Z + ((size_t)(c * CHs) * NF + n) * W + tid * 2;
    float sx = 0.f, sy = 0.f;
#pragma unroll 8
    for (int t = 0; t < CHs; ++t) {
        unsigned int u = *(const unsigned int*)(p + (size_t)t * NF * W);
        sx += lo16f(u);
        sy += hi16f(u);
    }
    float2* q = (float2*)&Cs[((size_t)c * NF + n) * W + tid * 2];
    *q = make_float2(sx, sy);
}

// ---------------------------------------------------------------------------
// Kernel 2b: exclusive prefix over chunks (+ cross-pass carry Gc, nbat==1).
// r15 contiguous mapping: lane = opair -> wave owns 128 consecutive cols,
// serial chunk walk, carry in regs, 8-deep prefetch. 512B wave ops.
// ---------------------------------------------------------------------------
__global__ __launch_bounds__(256, 4) void k_prefix(
    float* __restrict__ Cs, float* __restrict__ Gc,
    int W, int rr, int nch, int nbat)
{
    const int tid  = threadIdx.x;
    const int lane = tid & 63;
    const int obw  = W >> 7;                 // col-blocks of 128
    const int tasks = nbat * NF * obw;
    const int gw = blockIdx.x * 4 + (tid >> 6);
    if (gw >= tasks) return;
    const int perB = NF * obw;
    const int b    = gw / perB;
    const int rest = gw % perB;
    const int n    = rest / obw;
    const int ob   = rest % obw;
    const int opair = ob * 64 + lane;

    float* base = Cs + (size_t)b * nch * NF * W + (size_t)n * W + opair * 2;
    const size_t cstride = (size_t)NF * W;   // floats between chunks

    float cx = 0.f, cy = 0.f;
    if (nbat == 1 && rr != 0) {
        float2 g = *(const float2*)&Gc[(size_t)n * DOUT + opair * 2];
        cx = g.x; cy = g.y;
    }

    int c = 0;
    if (nch >= 16) {
        float2 v[8], w2[8];
#pragma unroll
        for (int k = 0; k < 8; ++k) v[k] = *(float2*)(base + (size_t)k * cstride);
        for (; c + 16 <= nch; c += 8) {
#pragma unroll
            for (int k = 0; k < 8; ++k)
                w2[k] = *(float2*)(base + (size_t)(c + 8 + k) * cstride);
#pragma unroll
            for (int k = 0; k < 8; ++k) {
                float2* p = (float2*)(base + (size_t)(c + k) * cstride);
                float2 t = v[k];
                *p = make_float2(cx, cy);
                cx += t.x; cy += t.y;
                v[k] = w2[k];
            }
        }
#pragma unroll
        for (int k = 0; k < 8; ++k) {
            float2* p = (float2*)(base + (size_t)(c + k) * cstride);
            float2 t = v[k];
            *p = make_float2(cx, cy);
            cx += t.x; cy += t.y;
        }
        c += 8;
    }
    for (; c < nch; ++c) {
        float2* p = (float2*)(base + (size_t)c * cstride);
        float2 t = *p;
        *p = make_float2(cx, cy);
        cx += t.x; cy += t.y;
    }

    if (nbat == 1)
        *(float2*)&Gc[(size_t)n * DOUT + opair * 2] = make_float2(cx, cy);
}

// ---------------------------------------------------------------------------
// Kernel 2c: scan + filter-weighted reduce. 4 waves x 6 filters; barrier
// batching (r11); uint2/lane 4-col vectorization (r15).
// grid (nch_total, ceil(W/256)), block 256.
// ---------------------------------------------------------------------------
#define JLIST(F) F(0) F(1) F(2) F(3) F(4) F(5)

__global__ __launch_bounds__(256, 4) void k_scan(
    const unsigned short* __restrict__ Z, const float* __restrict__ Cs,
    const float* __restrict__ Fw, float* __restrict__ Out,
    int r0, int o0, int W, int CHs)
{
    __shared__ float sPhi[32 * NF];
    __shared__ float4 sP[4][8][64];
    const int cg = blockIdx.x, tid = threadIdx.x;
    const int g = tid >> 6, op = tid & 63;
    const int ng0 = g * 6;
    const int c4  = (blockIdx.y * 64 + op) * 4;     // 4 cols per thread
    const int act = (c4 + 4 <= W);
    const int c4u = act ? c4 : (W - 4);             // clamped (harmless reads)
    const int t0g = r0 + cg * CHs;
    const int t0 = t0g & (TT - 1);
    for (int i = tid; i < CHs * NF; i += 256)
        sPhi[i] = Fw[(t0 + i / NF) * NF + (i % NF)];
    __syncthreads();

#define DECLG(j) float gA##j, gB##j, gC##j, gD##j;
    JLIST(DECLG)
#define INITG(j) { float4 v = *(const float4*)&Cs[((size_t)cg * NF + ng0 + j) * W + c4u]; \
                   gA##j = v.x; gB##j = v.y; gC##j = v.z; gD##j = v.w; }
    JLIST(INITG)

    const unsigned short* zp = Z + ((size_t)cg * CHs * NF + ng0) * W + c4u;
    float* outb = Out + (size_t)t0g * DOUT + o0 + c4;
    for (int tb = 0; tb < CHs; tb += 8) {
#pragma unroll
        for (int tt = 0; tt < 8; ++tt) {
            float a0 = 0.f, a1 = 0.f, a2 = 0.f, a3 = 0.f;
            const float* php = &sPhi[(tb + tt) * NF + ng0];
#define UPDG(j) { uint2 u = *(const uint2*)(zp + (size_t)j * W); \
                  gA##j += lo16f(u.x); gB##j += hi16f(u.x); \
                  gC##j += lo16f(u.y); gD##j += hi16f(u.y); \
                  float ph = php[j]; \
                  a0 += ph * gA##j; a1 += ph * gB##j; \
                  a2 += ph * gC##j; a3 += ph * gD##j; }
            JLIST(UPDG)
            sP[g][tt][op] = make_float4(a0, a1, a2, a3);
            zp += (size_t)NF * W;
        }
        __syncthreads();
#pragma unroll
        for (int k = 0; k < 2; ++k) {
            const int tt = g * 2 + k;
            float4 p0 = sP[0][tt][op], p1 = sP[1][tt][op],
                   p2 = sP[2][tt][op], p3 = sP[3][tt][op];
            if (act)
                *(float4*)(outb + (size_t)(tb + tt) * DOUT) =
                    make_float4(p0.x + p1.x + p2.x + p3.x,
                                p0.y + p1.y + p2.y + p3.y,
                                p0.z + p1.z + p2.z + p3.z,
                                p0.w + p1.w + p2.w + p3.w);
        }
        __syncthreads();
    }
}

// ---------------------------------------------------------------------------
extern "C" void kernel_launch(void* const* d_in, const int* in_sizes, int n_in,
                              void* d_out, int out_size, void* d_ws, size_t ws_size,
                              hipStream_t stream)
{
    const void* X = d_in[0]; const void* Fil = d_in[1]; const void* Mw = d_in[2];
    for (int i = 0; i < n_in && i < 3; ++i) {
        if (in_sizes[i] == BQ * TT * DF)        X   = d_in[i];
        else if (in_sizes[i] == TT * NF)        Fil = d_in[i];
        else if (in_sizes[i] == NF * DOUT * DF) Mw  = d_in[i];
    }
    float* Out = (float*)d_out;

    const size_t offF = 256;
    const size_t nbF  = (size_t)TT * NF * 4;
    const size_t off0 = offF + nbF;
    const size_t nbX  = (size_t)BQ * TT * DF * 2;    // 8.39 MB
    const size_t nbM  = (size_t)NF * DOUT * DF * 2;  // 12.58 MB
    const size_t nbGc = (size_t)NF * DOUT * 4;

    int* flag = (int*)d_ws;
    float* Fw = (float*)((char*)d_ws + offF);

    const int n4x = BQ * TT * DF / 4;
    const int n4m = NF * DOUT * DF / 4;
    const int n4f = TT * NF / 4;

    // ---- Multi-batch tiers: G batches per pass (G=4: Z 201 MB + Cs 50 MB;
    //      G=2: Z 101 MB + Cs 25 MB). Falls through to per-batch tier. ----
    for (int G = BQ; G >= 2; G >>= 1) {
        const size_t zB  = (size_t)G * TT * NF * 512 * 2;
        const size_t csB = (size_t)(G * TT / CHF) * NF * 512 * 4;
        if (off0 + nbX + nbM + zB + csB > ws_size) continue;

        unsigned short* Xbf = (unsigned short*)((char*)d_ws + off0);
        unsigned short* Mbf = (unsigned short*)((char*)Xbf + nbX);
        unsigned short* Z   = (unsigned short*)((char*)Mbf + nbM);
        float* Cs = (float*)((char*)Z + zB);

        hipLaunchKernelGGL(k_prep, dim3(2048), dim3(256), 0, stream,
                           X, Mw, Fil, Xbf, Mbf, Fw, n4x, n4m, n4f);

        const int nch = TT / CHF;            // per batch: 256
        for (int b0 = 0; b0 < BQ; b0 += G) {
            hipLaunchKernelGGL(k_gemm_fast, dim3(G * TT / 128, 4, NF), dim3(256),
                               0, stream, Xbf, Mbf, Fw, Z, Cs, b0 * TT);
            hipLaunchKernelGGL(k_prefix, dim3((G * NF * 4 + 3) / 4), dim3(256),
                               0, stream, Cs, (float*)nullptr, 512, 0, nch, G);
            hipLaunchKernelGGL(k_scan, dim3(G * nch, 2), dim3(256), 0, stream,
                               Z, Cs, Fw, Out, b0 * TT, 0, 512, CHF);
        }
        return;
    }

    // ---- Per-batch fused tier (proven >= 84 MB fits RT=2048) ----
    {
        static const int rts[5] = {2048, 1024, 512, 256, 128};
        int RT = 0;
        for (int ri = 0; ri < 5; ++ri) {
            size_t need = off0 + nbX + nbM
                        + (size_t)rts[ri] * NF * 512 * 2
                        + (size_t)(rts[ri] / CHF) * NF * 512 * 4 + nbGc;
            if (need <= ws_size) { RT = rts[ri]; break; }
        }
        if (RT > 0) {
            unsigned short* Xbf = (unsigned short*)((char*)d_ws + off0);
            unsigned short* Mbf = (unsigned short*)((char*)Xbf + nbX);
            unsigned short* Z   = (unsigned short*)((char*)Mbf + nbM);
            float* Cs = (float*)((char*)Z + (size_t)RT * NF * 512 * 2);
            float* Gc = (float*)((char*)Cs + (size_t)(RT / CHF) * NF * 512 * 4);

            hipLaunchKernelGGL(k_prep, dim3(2048), dim3(256), 0, stream,
                               X, Mw, Fil, Xbf, Mbf, Fw, n4x, n4m, n4f);

            const int nrr = TT / RT, nch = RT / CHF;
            for (int b = 0; b < BQ; ++b) {
                for (int rr = 0; rr < nrr; ++rr) {
                    const int r0 = b * TT + rr * RT;
                    hipLaunchKernelGGL(k_gemm_fast, dim3(RT / 128, 4, NF), dim3(256),
                                       0, stream, Xbf, Mbf, Fw, Z, Cs, r0);
                    hipLaunchKernelGGL(k_prefix, dim3((NF * 4 + 3) / 4), dim3(256),
                                       0, stream, Cs, Gc, 512, rr, nch, 1);
                    hipLaunchKernelGGL(k_scan, dim3(nch, 2), dim3(256), 0, stream,
                                       Z, Cs, Fw, Out, r0, 0, 512, CHF);
                }
            }
            return;
        }
    }

    // ---- Slow tiers (tiny ws): in-kernel convert GEMM, o-sliced, CH=32 ----
    hipLaunchKernelGGL(k_detect, dim3(1), dim3(64), 0, stream,
                       (const unsigned int*)X, flag);
    hipLaunchKernelGGL(k_convf, dim3(192), dim3(256), 0, stream,
                       Fil, Fw, flag, TT * NF);

    static const int cRT[7] = {2048, 1024, 512, 256, 128, 128, 128};
    static const int cW[7]  = {512, 512, 512, 512, 512, 256, 128};
    int RTs = 128, W = 128;
    for (int ci = 0; ci < 7; ++ci) {
        size_t need = off0 + (size_t)cRT[ci] * NF * cW[ci] * 2
                    + (size_t)(cRT[ci] / 32) * NF * cW[ci] * 4 + nbGc;
        if (need <= ws_size) { RTs = cRT[ci]; W = cW[ci]; break; }
    }
    unsigned short* Z = (unsigned short*)((char*)d_ws + off0);
    float* Cs = (float*)((char*)Z + (size_t)RTs * NF * W * 2);
    float* Gc = (float*)((char*)Cs + (size_t)(RTs / 32) * NF * W * 4);

    const int nrr = TT / RTs, nch = RTs / 32;
    for (int b = 0; b < BQ; ++b) {
        for (int o0 = 0; o0 < DOUT; o0 += W) {
            for (int rr = 0; rr < nrr; ++rr) {
                const int r0 = b * TT + rr * RTs;
                hipLaunchKernelGGL(k_gemm, dim3(RTs / 128, W / 128, NF), dim3(256),
                                   0, stream, X, Mw, Fil, flag, Z, r0, o0, W);
                hipLaunchKernelGGL(k_csum, dim3(nch, NF), dim3(W / 2), 0, stream,
                                   Z, Cs, W, 32);
                hipLaunchKernelGGL(k_prefix, dim3((NF * (W / 128) + 3) / 4), dim3(256),
                                   0, stream, Cs, Gc, W, rr, nch, 1);
                hipLaunchKernelGGL(k_scan, dim3(nch, (W + 255) / 256), dim3(256),
                                   0, stream, Z, Cs, Fw, Out, r0, o0, W, 32);
            }
        }
    }
}

// Round 7
// 319.376 us; speedup vs baseline: 1.0443x; 1.0443x over previous
//
#include <hip/hip_runtime.h>
#include <stdint.h>

// Problem: B=4, T=2048, D_IN=512, D_OUT=512, N_FILT=24.
// Inputs fp32 (runtime-detected, bf16 fallback). Output fp32.
// out[b,t,o] = sum_n phi[t,n] * cumsum_t( phi[t,n] * (M[n] @ x[b,t,:]) )[o]
#define BQ 4
#define TT 2048
#define DF 512
#define DOUT 512
#define NF 24
#define CHF 8   // fast-path scan chunk (rows)

typedef __attribute__((ext_vector_type(8))) short short8;
typedef __attribute__((ext_vector_type(4))) float f32x4;

typedef __attribute__((address_space(3))) uint8_t       lds_u8;
typedef __attribute__((address_space(1))) const uint8_t glb_u8;

__device__ __forceinline__ float bf2f(unsigned short u) {
    union { unsigned int i; float f; } v; v.i = ((unsigned int)u) << 16; return v.f;
}
__device__ __forceinline__ unsigned short f2bf(float f) {
    union { float f; unsigned int i; } v; v.f = f;
    unsigned int r = v.i + 0x7FFFu + ((v.i >> 16) & 1u);  // RNE
    return (unsigned short)(r >> 16);
}
__device__ __forceinline__ float lo16f(unsigned int u) { return __uint_as_float(u << 16); }
__device__ __forceinline__ float hi16f(unsigned int u) { return __uint_as_float(u & 0xffff0000u); }

// ---------------------------------------------------------------------------
// Dtype sniffer (flag=1 => fp32 inputs).
// ---------------------------------------------------------------------------
__device__ __forceinline__ int plaus16(unsigned int h) {
    unsigned int e = (h >> 7) & 0xffu;
    return (e >= 97u && e <= 141u) || ((h & 0x7fffu) == 0u);
}

__global__ void k_detect(const unsigned int* __restrict__ X, int* __restrict__ flag)
{
    const int lane = threadIdx.x;  // 64 threads, 1 block
    int cnt = 0;
#pragma unroll
    for (int i = 0; i < 4; ++i) {
        unsigned int w = X[lane * 4 + i];
        cnt += (plaus16(w >> 16) && plaus16(w & 0xffffu)) ? 1 : 0;
    }
    for (int off = 32; off > 0; off >>= 1) cnt += __shfl_down(cnt, off);
    if (lane == 0) *flag = (cnt < 180) ? 1 : 0;
}

__global__ __launch_bounds__(256) void k_convf(
    const void* __restrict__ src, float* __restrict__ dst,
    const int* __restrict__ flag, int n)
{
    const int isf32 = *flag;
    int i = blockIdx.x * 256 + threadIdx.x;
    const int stride = gridDim.x * 256;
    for (; i < n; i += stride)
        dst[i] = isf32 ? ((const float*)src)[i]
                       : bf2f(((const unsigned short*)src)[i]);
}

// ---------------------------------------------------------------------------
// r16: ONE prep kernel replacing detect + convf + convertX + convertM.
// Each block self-computes the dtype flag from X's first 1KB.
// ---------------------------------------------------------------------------
__global__ __launch_bounds__(256) void k_prep(
    const void* __restrict__ X, const void* __restrict__ Mw,
    const void* __restrict__ Fil,
    unsigned short* __restrict__ Xbf, unsigned short* __restrict__ Mbf,
    float* __restrict__ Fw, int n4x, int n4m, int n4f)
{
    __shared__ int sflag;
    const int tid = threadIdx.x;
    if (tid < 64) {
        int cnt = 0;
        const unsigned int* Xu = (const unsigned int*)X;
#pragma unroll
        for (int i = 0; i < 4; ++i) {
            unsigned int wd = Xu[tid * 4 + i];
            cnt += (plaus16(wd >> 16) && plaus16(wd & 0xffffu)) ? 1 : 0;
        }
        for (int off = 32; off > 0; off >>= 1) cnt += __shfl_down(cnt, off);
        if (tid == 0) sflag = (cnt < 180) ? 1 : 0;
    }
    __syncthreads();
    const int isf32 = sflag;

    const int total = n4x + n4m + n4f;
    for (int i = blockIdx.x * 256 + tid; i < total; i += gridDim.x * 256) {
        if (i < n4x) {
            ushort4 o;
            if (isf32) {
                float4 v = ((const float4*)X)[i];
                o.x = f2bf(v.x); o.y = f2bf(v.y); o.z = f2bf(v.z); o.w = f2bf(v.w);
            } else {
                o = ((const ushort4*)X)[i];
            }
            ((ushort4*)Xbf)[i] = o;
        } else if (i < n4x + n4m) {
            const int j = i - n4x;
            ushort4 o;
            if (isf32) {
                float4 v = ((const float4*)Mw)[j];
                o.x = f2bf(v.x); o.y = f2bf(v.y); o.z = f2bf(v.z); o.w = f2bf(v.w);
            } else {
                o = ((const ushort4*)Mw)[j];
            }
            ((ushort4*)Mbf)[j] = o;
        } else {
            const int j = i - n4x - n4m;
            if (isf32) {
                ((float4*)Fw)[j] = ((const float4*)Fil)[j];
            } else {
                ushort4 u = ((const ushort4*)Fil)[j];
                ((float4*)Fw)[j] = make_float4(bf2f(u.x), bf2f(u.y),
                                               bf2f(u.z), bf2f(u.w));
            }
        }
    }
}

// ---------------------------------------------------------------------------
// FAST GEMM, fused chunk-sums. m97 pattern + XOR bank swizzle (r10) +
// r12 2-phase dbuf. r17: XCD swizzle REVERTED (r16 A/B: FETCH 54.7->91 MB,
// dur 74.4->79.5 — contiguous-per-XCD made each XCD serially re-walk X,
// thrashing its 4MB L2; the linear mapping's time-concurrent panel blocks
// were already the better L2 pattern).
// grid (rows/128, 4, NF), block 256.
// ---------------------------------------------------------------------------
__global__ __launch_bounds__(256, 3) void k_gemm_fast(
    const unsigned short* __restrict__ X,   // bf16 [B*T, DF]
    const unsigned short* __restrict__ Mw,  // bf16 [NF][DOUT][DF]
    const float* __restrict__ Fw,           // fp32 [TT][NF]
    unsigned short* __restrict__ Z,         // bf16 [rl][n][512]
    float* __restrict__ Cs,                 // fp32 [chunk][n][512]
    int r0)
{
    // union: dbuf {buf0: A[4096] B[4096] | buf1: A B} (16384 shorts) / sC (17408)
    __shared__ unsigned short sAB[128 * 136];
    __shared__ float sPhi[128];
    unsigned short* const sC = sAB;

    const int tid  = threadIdx.x;
    const int lane = tid & 63;
    const int w    = tid >> 6;
    const int wm   = w & 1, wn = w >> 1;
    const int tm   = blockIdx.x;
    const int on0  = blockIdx.y * 128;
    const int n    = blockIdx.z;

    const int rowg0 = r0 + tm * 128;
    if (tid < 128)
        sPhi[tid] = Fw[((rowg0 + tid) & (TT - 1)) * NF + n];

    const unsigned short* Ag = X + (size_t)rowg0 * DF;
    const unsigned short* Bg = Mw + (size_t)n * DOUT * DF + (size_t)on0 * DF;

    // Per-thread staging geometry (16B slots; XOR bank swizzle on source)
    auto stage = [&](int kt, int buf) {
        const unsigned short* Ak = Ag + kt * 32;
        const unsigned short* Bk = Bg + kt * 32;
        lds_u8* base = (lds_u8*)sAB + buf * 16384;
#pragma unroll
        for (int i = 0; i < 2; ++i) {
            const int cbase = i * 256 + w * 64;   // wave-uniform 16B-slot base
            const int c = cbase + lane;           // this lane's LDS slot
            const int r = c >> 2, qs = c & 3;
            const int qg = qs ^ ((r >> 1) & 3);   // swizzle: slot qs holds chunk qg
            __builtin_amdgcn_global_load_lds(
                (const glb_u8*)(Ak + (size_t)r * DF + qg * 8),
                base + cbase * 16, 16, 0, 0);
            __builtin_amdgcn_global_load_lds(
                (const glb_u8*)(Bk + (size_t)r * DF + qg * 8),
                base + 8192 + cbase * 16, 16, 0, 0);
        }
    };

    f32x4 acc[4][4];
#pragma unroll
    for (int i = 0; i < 4; i++)
#pragma unroll
        for (int j = 0; j < 4; j++) acc[i][j] = (f32x4){0.f, 0.f, 0.f, 0.f};

    stage(0, 0);
    __syncthreads();   // vmcnt(0) drain: buf0 ready

    const int lr = lane & 15;
    const int q  = lane >> 4;
    const int qsw = (q ^ ((lr >> 1) & 3)) * 8;    // (row>>1)&3 == (lr>>1)&3

    for (int kt = 0; kt < DF / 32; ++kt) {
        const int cur = kt & 1;
        if (kt < DF / 32 - 1) stage(kt + 1, cur ^ 1);   // loads in flight over compute

        const unsigned short* sAc = sAB + cur * 8192;
        const unsigned short* sBc = sAc + 4096;
        short8 a[4], b[4];
#pragma unroll
        for (int i = 0; i < 4; i++)
            a[i] = *(const short8*)&sAc[(wm * 64 + i * 16 + lr) * 32 + qsw];
#pragma unroll
        for (int j = 0; j < 4; j++)
            b[j] = *(const short8*)&sBc[(wn * 64 + j * 16 + lr) * 32 + qsw];
#pragma unroll
        for (int i = 0; i < 4; i++)
#pragma unroll
            for (int j = 0; j < 4; j++)
                acc[i][j] = __builtin_amdgcn_mfma_f32_16x16x32_bf16(
                    a[i], b[j], acc[i][j], 0, 0, 0);

        __syncthreads();   // drains this iter's stage + guards buf reuse
    }
    // last loop barrier passed: all ds_reads complete, sC may overlay dbuf

    // C/D layout (m89/m91-verified): col = lane&15, row = (lane>>4)*4 + reg
    const int rb = (lane >> 4) * 4;
#pragma unroll
    for (int i = 0; i < 4; i++)
#pragma unroll
        for (int j = 0; j < 4; j++)
#pragma unroll
            for (int r = 0; r < 4; r++) {
                int row = wm * 64 + i * 16 + rb + r;
                sC[row * 136 + wn * 64 + j * 16 + (lane & 15)] =
                    f2bf(acc[i][j][r] * sPhi[row]);
            }
    __syncthreads();

    // Z store (coalesced 16B)
#pragma unroll
    for (int it = 0; it < 8; ++it) {
        int row = it * 16 + (tid >> 4);
        int col = (tid & 15) * 8;
        uint4 v = *(const uint4*)&sC[row * 136 + col];
        *(uint4*)&Z[((size_t)(tm * 128 + row) * NF + n) * 512 + on0 + col] = v;
    }

    // Fused chunk sums: 16 chunks x 128 cols; thread -> (chunk ci, 8 cols).
    {
        const int ci  = tid >> 4;           // chunk within tile, 0..15
        const int col = (tid & 15) * 8;
        float s0=0.f,s1=0.f,s2=0.f,s3=0.f,s4=0.f,s5=0.f,s6=0.f,s7=0.f;
#pragma unroll
        for (int r = 0; r < CHF; ++r) {
            uint4 v = *(const uint4*)&sC[(ci * CHF + r) * 136 + col];
            s0 += lo16f(v.x); s1 += hi16f(v.x);
            s2 += lo16f(v.y); s3 += hi16f(v.y);
            s4 += lo16f(v.z); s5 += hi16f(v.z);
            s6 += lo16f(v.w); s7 += hi16f(v.w);
        }
        float* cp = &Cs[((size_t)(tm * 16 + ci) * NF + n) * 512 + on0 + col];
        *(float4*)cp       = make_float4(s0, s1, s2, s3);
        *(float4*)(cp + 4) = make_float4(s4, s5, s6, s7);
    }
}

// ---------------------------------------------------------------------------
// SLOW GEMM (fallback for tiny ws): register staging + in-flight convert.
// ---------------------------------------------------------------------------
__global__ __launch_bounds__(256, 2) void k_gemm(
    const void* __restrict__ Xv, const void* __restrict__ Mv,
    const void* __restrict__ Fv, const int* __restrict__ flag,
    unsigned short* __restrict__ Z, int r0, int o0, int W)
{
    __shared__ unsigned short sA[128 * 32];
    __shared__ unsigned short sB[128 * 32];
    __shared__ unsigned short sC[128 * 136];
    __shared__ float sPhi[128];

    const int isf32 = *flag;
    const int tid  = threadIdx.x;
    const int lane = tid & 63;
    const int w    = tid >> 6;
    const int wm   = w & 1, wn = w >> 1;
    const int tm   = blockIdx.x;
    const int on0  = o0 + blockIdx.y * 128;
    const int n    = blockIdx.z;

    const int rowg0 = r0 + tm * 128;
    if (tid < 128) {
        int t = (rowg0 + tid) & (TT - 1);
        sPhi[tid] = isf32 ? ((const float*)Fv)[t * NF + n]
                          : bf2f(((const unsigned short*)Fv)[t * NF + n]);
    }

    const unsigned short* Ah = (const unsigned short*)Xv + (size_t)rowg0 * DF;
    const unsigned short* Bh = (const unsigned short*)Mv +
        (size_t)n * DOUT * DF + (size_t)on0 * DF;
    const float* Af = (const float*)Xv + (size_t)rowg0 * DF;
    const float* Bf = (const float*)Mv + (size_t)n * DOUT * DF + (size_t)on0 * DF;

    f32x4 acc[4][4];
#pragma unroll
    for (int i = 0; i < 4; i++)
#pragma unroll
        for (int j = 0; j < 4; j++) acc[i][j] = (f32x4){0.f, 0.f, 0.f, 0.f};

    for (int kt = 0; kt < DF / 32; ++kt) {
        __syncthreads();
        if (!isf32) {
            const unsigned short* Ak = Ah + kt * 32;
            const unsigned short* Bk = Bh + kt * 32;
#pragma unroll
            for (int i = 0; i < 2; ++i) {
                const int c = i * 256 + tid;
                const int r = c >> 2, cc = (c & 3) * 8;
                *(short8*)&sA[r * 32 + cc] = *(const short8*)(Ak + (size_t)r * DF + cc);
                *(short8*)&sB[r * 32 + cc] = *(const short8*)(Bk + (size_t)r * DF + cc);
            }
        } else {
            const float* Ak = Af + kt * 32;
            const float* Bk = Bf + kt * 32;
#pragma unroll
            for (int i = 0; i < 2; ++i) {
                const int c = i * 256 + tid;
                const int r = c >> 2, cc = (c & 3) * 8;
                float4 a0 = *(const float4*)(Ak + (size_t)r * DF + cc);
                float4 a1 = *(const float4*)(Ak + (size_t)r * DF + cc + 4);
                float4 b0 = *(const float4*)(Bk + (size_t)r * DF + cc);
                float4 b1 = *(const float4*)(Bk + (size_t)r * DF + cc + 4);
                short8 sa, sb;
                sa[0]=(short)f2bf(a0.x); sa[1]=(short)f2bf(a0.y);
                sa[2]=(short)f2bf(a0.z); sa[3]=(short)f2bf(a0.w);
                sa[4]=(short)f2bf(a1.x); sa[5]=(short)f2bf(a1.y);
                sa[6]=(short)f2bf(a1.z); sa[7]=(short)f2bf(a1.w);
                sb[0]=(short)f2bf(b0.x); sb[1]=(short)f2bf(b0.y);
                sb[2]=(short)f2bf(b0.z); sb[3]=(short)f2bf(b0.w);
                sb[4]=(short)f2bf(b1.x); sb[5]=(short)f2bf(b1.y);
                sb[6]=(short)f2bf(b1.z); sb[7]=(short)f2bf(b1.w);
                *(short8*)&sA[r * 32 + cc] = sa;
                *(short8*)&sB[r * 32 + cc] = sb;
            }
        }
        __syncthreads();

        const int lr = lane & 15;
        const int lk = (lane >> 4) * 8;
        short8 a[4], b[4];
#pragma unroll
        for (int i = 0; i < 4; i++)
            a[i] = *(const short8*)&sA[(wm * 64 + i * 16 + lr) * 32 + lk];
#pragma unroll
        for (int j = 0; j < 4; j++)
            b[j] = *(const short8*)&sB[(wn * 64 + j * 16 + lr) * 32 + lk];
#pragma unroll
        for (int i = 0; i < 4; i++)
#pragma unroll
            for (int j = 0; j < 4; j++)
                acc[i][j] = __builtin_amdgcn_mfma_f32_16x16x32_bf16(
                    a[i], b[j], acc[i][j], 0, 0, 0);
    }

    const int rb = (lane >> 4) * 4;
#pragma unroll
    for (int i = 0; i < 4; i++)
#pragma unroll
        for (int j = 0; j < 4; j++)
#pragma unroll
            for (int r = 0; r < 4; r++) {
                int row = wm * 64 + i * 16 + rb + r;
                sC[row * 136 + wn * 64 + j * 16 + (lane & 15)] =
                    f2bf(acc[i][j][r] * sPhi[row]);
            }
    __syncthreads();
#pragma unroll
    for (int it = 0; it < 8; ++it) {
        int row = it * 16 + (tid >> 4);
        int col = (tid & 15) * 8;
        uint4 v = *(const uint4*)&sC[row * 136 + col];
        *(uint4*)&Z[((size_t)(tm * 128 + row) * NF + n) * W + (on0 - o0) + col] = v;
    }
}

// ---------------------------------------------------------------------------
// Kernel 2a (slow tier only): chunk sums. grid (nch, NF), block W/2.
// ---------------------------------------------------------------------------
__global__ __launch_bounds__(256, 2) void k_csum(
    const unsigned short* __restrict__ Z, float* __restrict__ Cs,
    int W, int CHs)
{
    const int c = blockIdx.x, n = blockIdx.y, tid = threadIdx.x;
    const unsigned short* p = Z + ((size_t)(c * CHs) * NF + n) * W + tid * 2;
    float sx = 0.f, sy = 0.f;
#pragma unroll 8
    for (int t = 0; t < CHs; ++t) {
        unsigned int u = *(const unsigned int*)(p + (size_t)t * NF * W);
        sx += lo16f(u);
        sy += hi16f(u);
    }
    float2* q = (float2*)&Cs[((size_t)c * NF + n) * W + tid * 2];
    *q = make_float2(sx, sy);
}

// ---------------------------------------------------------------------------
// Kernel 2b: exclusive prefix over chunks (+ cross-pass carry Gc, nbat==1).
// r17: cooperative block per column-strip. Old r15 form: ONE wave serially
// RMW-walked all nch chunks (8-deep prefetch) => serial depth 256 ~ 19us.
// New: 4 waves split the chunk range in quarters:
//   P1 each wave SUMS its quarter (pure loads, fully pipelined)
//   P2 LDS-exchange partials -> per-wave carry (+ Gc)
//   P3 each wave exclusive-walks its own quarter (8-deep prefetch)
// Serial depth 256 -> 64 (+ one extra read pass). Quarter-partial regroup
// is a rounding-level change only. grid = nbat*NF*(W/128) blocks of 256.
// ---------------------------------------------------------------------------
__global__ __launch_bounds__(256, 4) void k_prefix(
    float* __restrict__ Cs, float* __restrict__ Gc,
    int W, int rr, int nch, int nbat)
{
    __shared__ float2 sPart[4][64];
    const int tid  = threadIdx.x;
    const int wv   = tid >> 6, lane = tid & 63;
    const int obw  = W >> 7;                 // col-blocks of 128
    const int perB = NF * obw;
    const int gw   = blockIdx.x;
    const int b    = gw / perB;
    const int rest = gw % perB;
    const int n    = rest / obw;
    const int ob   = rest % obw;
    const int opair = ob * 64 + lane;

    float* base = Cs + (size_t)b * nch * NF * W + (size_t)n * W + opair * 2;
    const size_t cstride = (size_t)NF * W;   // floats between chunks
    const int Q  = nch >> 2;                 // nch is pow2 >= 4 in all tiers
    const int c0 = wv * Q;
    const int end = c0 + Q;

    // P1: wave-local sum of own quarter (independent loads, MLP-friendly)
    float sx = 0.f, sy = 0.f;
    for (int c = c0; c < end; ++c) {
        float2 v = *(const float2*)(base + (size_t)c * cstride);
        sx += v.x; sy += v.y;
    }
    sPart[wv][lane] = make_float2(sx, sy);
    __syncthreads();

    // P2: carry = Gc (cross-pass) + lower quarters
    float cx = 0.f, cy = 0.f;
    if (nbat == 1 && rr != 0) {
        float2 gv = *(const float2*)&Gc[(size_t)n * DOUT + opair * 2];
        cx = gv.x; cy = gv.y;
    }
    for (int w2 = 0; w2 < wv; ++w2) {
        float2 p = sPart[w2][lane];
        cx += p.x; cy += p.y;
    }

    // P3: exclusive walk over own quarter (8-deep prefetch when Q>=16)
    int c = c0;
    if (Q >= 16) {
        float2 v[8], nx[8];
#pragma unroll
        for (int k = 0; k < 8; ++k)
            v[k] = *(float2*)(base + (size_t)(c + k) * cstride);
        for (; c + 16 <= end; c += 8) {
#pragma unroll
            for (int k = 0; k < 8; ++k)
                nx[k] = *(float2*)(base + (size_t)(c + 8 + k) * cstride);
#pragma unroll
            for (int k = 0; k < 8; ++k) {
                float2* p = (float2*)(base + (size_t)(c + k) * cstride);
                float2 t = v[k];
                *p = make_float2(cx, cy);
                cx += t.x; cy += t.y;
                v[k] = nx[k];
            }
        }
#pragma unroll
        for (int k = 0; k < 8; ++k) {
            float2* p = (float2*)(base + (size_t)(c + k) * cstride);
            float2 t = v[k];
            *p = make_float2(cx, cy);
            cx += t.x; cy += t.y;
        }
        c += 8;
    }
    for (; c < end; ++c) {
        float2* p = (float2*)(base + (size_t)c * cstride);
        float2 t = *p;
        *p = make_float2(cx, cy);
        cx += t.x; cy += t.y;
    }

    // top wave's final carry = inclusive grand total for this pass
    if (nbat == 1 && wv == 3)
        *(float2*)&Gc[(size_t)n * DOUT + opair * 2] = make_float2(cx, cy);
}

// ---------------------------------------------------------------------------
// Kernel 2c: scan + filter-weighted reduce. 4 waves x 6 filters; barrier
// batching (r11). r17: 2 cols/thread (uint loads) + grid.y doubled + sP
// float2 (LDS 19.4KB) + launch_bounds(256,8) -> 2048 blocks, 8 blocks/CU,
// 32 waves/CU (was 16): the kernel is latency-bound (48 strided loads per
// thread vs 19us BW floor, ran ~60us) — 2x TLP + halved per-thread state
// (12 floats, was 24 at the VGPR=64 cap).
// grid (nch_total, W/128), block 256.
// ---------------------------------------------------------------------------
#define JLIST(F) F(0) F(1) F(2) F(3) F(4) F(5)

__global__ __launch_bounds__(256, 8) void k_scan(
    const unsigned short* __restrict__ Z, const float* __restrict__ Cs,
    const float* __restrict__ Fw, float* __restrict__ Out,
    int r0, int o0, int W, int CHs)
{
    __shared__ float sPhi[32 * NF];
    __shared__ float2 sP[4][8][64];
    const int cg = blockIdx.x, tid = threadIdx.x;
    const int g = tid >> 6, op = tid & 63;
    const int ng0 = g * 6;
    const int c2  = (blockIdx.y * 64 + op) * 2;     // 2 cols per thread
    const int act = (c2 + 2 <= W);
    const int c2u = act ? c2 : (W - 2);             // clamped (harmless reads)
    const int t0g = r0 + cg * CHs;
    const int t0 = t0g & (TT - 1);
    for (int i = tid; i < CHs * NF; i += 256)
        sPhi[i] = Fw[(t0 + i / NF) * NF + (i % NF)];
    __syncthreads();

#define DECLG(j) float gx##j, gy##j;
    JLIST(DECLG)
#define INITG(j) { float2 v = *(const float2*)&Cs[((size_t)cg * NF + ng0 + j) * W + c2u]; \
                   gx##j = v.x; gy##j = v.y; }
    JLIST(INITG)

    const unsigned short* zp = Z + ((size_t)cg * CHs * NF + ng0) * W + c2u;
    float* outb = Out + (size_t)t0g * DOUT + o0 + c2;
    for (int tb = 0; tb < CHs; tb += 8) {
#pragma unroll
        for (int tt = 0; tt < 8; ++tt) {
            float ax = 0.f, ay = 0.f;
            const float* php = &sPhi[(tb + tt) * NF + ng0];
#define UPDG(j) { unsigned int u = *(const unsigned int*)(zp + (size_t)j * W); \
                  gx##j += lo16f(u); gy##j += hi16f(u); \
                  float ph = php[j]; ax += ph * gx##j; ay += ph * gy##j; }
            JLIST(UPDG)
            sP[g][tt][op] = make_float2(ax, ay);
            zp += (size_t)NF * W;
        }
        __syncthreads();
#pragma unroll
        for (int k = 0; k < 2; ++k) {
            const int tt = g * 2 + k;
            float2 p0 = sP[0][tt][op], p1 = sP[1][tt][op],
                   p2 = sP[2][tt][op], p3 = sP[3][tt][op];
            if (act)
                *(float2*)(outb + (size_t)(tb + tt) * DOUT) =
                    make_float2(p0.x + p1.x + p2.x + p3.x,
                                p0.y + p1.y + p2.y + p3.y);
        }
        __syncthreads();
    }
}

// ---------------------------------------------------------------------------
extern "C" void kernel_launch(void* const* d_in, const int* in_sizes, int n_in,
                              void* d_out, int out_size, void* d_ws, size_t ws_size,
                              hipStream_t stream)
{
    const void* X = d_in[0]; const void* Fil = d_in[1]; const void* Mw = d_in[2];
    for (int i = 0; i < n_in && i < 3; ++i) {
        if (in_sizes[i] == BQ * TT * DF)        X   = d_in[i];
        else if (in_sizes[i] == TT * NF)        Fil = d_in[i];
        else if (in_sizes[i] == NF * DOUT * DF) Mw  = d_in[i];
    }
    float* Out = (float*)d_out;

    const size_t offF = 256;
    const size_t nbF  = (size_t)TT * NF * 4;
    const size_t off0 = offF + nbF;
    const size_t nbX  = (size_t)BQ * TT * DF * 2;    // 8.39 MB
    const size_t nbM  = (size_t)NF * DOUT * DF * 2;  // 12.58 MB
    const size_t nbGc = (size_t)NF * DOUT * 4;

    int* flag = (int*)d_ws;
    float* Fw = (float*)((char*)d_ws + offF);

    const int n4x = BQ * TT * DF / 4;
    const int n4m = NF * DOUT * DF / 4;
    const int n4f = TT * NF / 4;

    // ---- Multi-batch tiers: G batches per pass (G=4: Z 201 MB + Cs 50 MB;
    //      G=2: Z 101 MB + Cs 25 MB). Falls through to per-batch tier. ----
    for (int G = BQ; G >= 2; G >>= 1) {
        const size_t zB  = (size_t)G * TT * NF * 512 * 2;
        const size_t csB = (size_t)(G * TT / CHF) * NF * 512 * 4;
        if (off0 + nbX + nbM + zB + csB > ws_size) continue;

        unsigned short* Xbf = (unsigned short*)((char*)d_ws + off0);
        unsigned short* Mbf = (unsigned short*)((char*)Xbf + nbX);
        unsigned short* Z   = (unsigned short*)((char*)Mbf + nbM);
        float* Cs = (float*)((char*)Z + zB);

        hipLaunchKernelGGL(k_prep, dim3(2048), dim3(256), 0, stream,
                           X, Mw, Fil, Xbf, Mbf, Fw, n4x, n4m, n4f);

        const int nch = TT / CHF;            // per batch: 256
        for (int b0 = 0; b0 < BQ; b0 += G) {
            hipLaunchKernelGGL(k_gemm_fast, dim3(G * TT / 128, 4, NF), dim3(256),
                               0, stream, Xbf, Mbf, Fw, Z, Cs, b0 * TT);
            hipLaunchKernelGGL(k_prefix, dim3(G * NF * 4), dim3(256),
                               0, stream, Cs, (float*)nullptr, 512, 0, nch, G);
            hipLaunchKernelGGL(k_scan, dim3(G * nch, 4), dim3(256), 0, stream,
                               Z, Cs, Fw, Out, b0 * TT, 0, 512, CHF);
        }
        return;
    }

    // ---- Per-batch fused tier (proven >= 84 MB fits RT=2048) ----
    {
        static const int rts[5] = {2048, 1024, 512, 256, 128};
        int RT = 0;
        for (int ri = 0; ri < 5; ++ri) {
            size_t need = off0 + nbX + nbM
                        + (size_t)rts[ri] * NF * 512 * 2
                        + (size_t)(rts[ri] / CHF) * NF * 512 * 4 + nbGc;
            if (need <= ws_size) { RT = rts[ri]; break; }
        }
        if (RT > 0) {
            unsigned short* Xbf = (unsigned short*)((char*)d_ws + off0);
            unsigned short* Mbf = (unsigned short*)((char*)Xbf + nbX);
            unsigned short* Z   = (unsigned short*)((char*)Mbf + nbM);
            float* Cs = (float*)((char*)Z + (size_t)RT * NF * 512 * 2);
            float* Gc = (float*)((char*)Cs + (size_t)(RT / CHF) * NF * 512 * 4);

            hipLaunchKernelGGL(k_prep, dim3(2048), dim3(256), 0, stream,
                               X, Mw, Fil, Xbf, Mbf, Fw, n4x, n4m, n4f);

            const int nrr = TT / RT, nch = RT / CHF;
            for (int b = 0; b < BQ; ++b) {
                for (int rr = 0; rr < nrr; ++rr) {
                    const int r0 = b * TT + rr * RT;
                    hipLaunchKernelGGL(k_gemm_fast, dim3(RT / 128, 4, NF), dim3(256),
                                       0, stream, Xbf, Mbf, Fw, Z, Cs, r0);
                    hipLaunchKernelGGL(k_prefix, dim3(NF * 4), dim3(256),
                                       0, stream, Cs, Gc, 512, rr, nch, 1);
                    hipLaunchKernelGGL(k_scan, dim3(nch, 4), dim3(256), 0, stream,
                                       Z, Cs, Fw, Out, r0, 0, 512, CHF);
                }
            }
            return;
        }
    }

    // ---- Slow tiers (tiny ws): in-kernel convert GEMM, o-sliced, CH=32 ----
    hipLaunchKernelGGL(k_detect, dim3(1), dim3(64), 0, stream,
                       (const unsigned int*)X, flag);
    hipLaunchKernelGGL(k_convf, dim3(192), dim3(256), 0, stream,
                       Fil, Fw, flag, TT * NF);

    static const int cRT[7] = {2048, 1024, 512, 256, 128, 128, 128};
    static const int cW[7]  = {512, 512, 512, 512, 512, 256, 128};
    int RTs = 128, W = 128;
    for (int ci = 0; ci < 7; ++ci) {
        size_t need = off0 + (size_t)cRT[ci] * NF * cW[ci] * 2
                    + (size_t)(cRT[ci] / 32) * NF * cW[ci] * 4 + nbGc;
        if (need <= ws_size) { RTs = cRT[ci]; W = cW[ci]; break; }
    }
    unsigned short* Z = (unsigned short*)((char*)d_ws + off0);
    float* Cs = (float*)((char*)Z + (size_t)RTs * NF * W * 2);
    float* Gc = (float*)((char*)Cs + (size_t)(RTs / 32) * NF * W * 4);

    const int nrr = TT / RTs, nch = RTs / 32;
    for (int b = 0; b < BQ; ++b) {
        for (int o0 = 0; o0 < DOUT; o0 += W) {
            for (int rr = 0; rr < nrr; ++rr) {
                const int r0 = b * TT + rr * RTs;
                hipLaunchKernelGGL(k_gemm, dim3(RTs / 128, W / 128, NF), dim3(256),
                                   0, stream, X, Mw, Fil, flag, Z, r0, o0, W);
                hipLaunchKernelGGL(k_csum, dim3(nch, NF), dim3(W / 2), 0, stream,
                                   Z, Cs, W, 32);
                hipLaunchKernelGGL(k_prefix, dim3(NF * (W / 128)), dim3(256),
                                   0, stream, Cs, Gc, W, rr, nch, 1);
                hipLaunchKernelGGL(k_scan, dim3(nch, W / 128), dim3(256),
                                   0, stream, Z, Cs, Fw, Out, r0, o0, W, 32);
            }
        }
    }
}

// Round 8
// 313.997 us; speedup vs baseline: 1.0622x; 1.0171x over previous
//
#include <hip/hip_runtime.h>
#include <stdint.h>

// Problem: B=4, T=2048, D_IN=512, D_OUT=512, N_FILT=24.
// Inputs fp32 (runtime-detected, bf16 fallback). Output fp32.
// out[b,t,o] = sum_n phi[t,n] * cumsum_t( phi[t,n] * (M[n] @ x[b,t,:]) )[o]
#define BQ 4
#define TT 2048
#define DF 512
#define DOUT 512
#define NF 24
#define CHF 8   // fast-path scan chunk (rows)

typedef __attribute__((ext_vector_type(8))) short short8;
typedef __attribute__((ext_vector_type(4))) float f32x4;

typedef __attribute__((address_space(3))) uint8_t       lds_u8;
typedef __attribute__((address_space(1))) const uint8_t glb_u8;

__device__ __forceinline__ float bf2f(unsigned short u) {
    union { unsigned int i; float f; } v; v.i = ((unsigned int)u) << 16; return v.f;
}
__device__ __forceinline__ unsigned short f2bf(float f) {
    union { float f; unsigned int i; } v; v.f = f;
    unsigned int r = v.i + 0x7FFFu + ((v.i >> 16) & 1u);  // RNE
    return (unsigned short)(r >> 16);
}
__device__ __forceinline__ float lo16f(unsigned int u) { return __uint_as_float(u << 16); }
__device__ __forceinline__ float hi16f(unsigned int u) { return __uint_as_float(u & 0xffff0000u); }

// ---------------------------------------------------------------------------
// Dtype sniffer (flag=1 => fp32 inputs).
// ---------------------------------------------------------------------------
__device__ __forceinline__ int plaus16(unsigned int h) {
    unsigned int e = (h >> 7) & 0xffu;
    return (e >= 97u && e <= 141u) || ((h & 0x7fffu) == 0u);
}

__global__ void k_detect(const unsigned int* __restrict__ X, int* __restrict__ flag)
{
    const int lane = threadIdx.x;  // 64 threads, 1 block
    int cnt = 0;
#pragma unroll
    for (int i = 0; i < 4; ++i) {
        unsigned int w = X[lane * 4 + i];
        cnt += (plaus16(w >> 16) && plaus16(w & 0xffffu)) ? 1 : 0;
    }
    for (int off = 32; off > 0; off >>= 1) cnt += __shfl_down(cnt, off);
    if (lane == 0) *flag = (cnt < 180) ? 1 : 0;
}

__global__ __launch_bounds__(256) void k_convf(
    const void* __restrict__ src, float* __restrict__ dst,
    const int* __restrict__ flag, int n)
{
    const int isf32 = *flag;
    int i = blockIdx.x * 256 + threadIdx.x;
    const int stride = gridDim.x * 256;
    for (; i < n; i += stride)
        dst[i] = isf32 ? ((const float*)src)[i]
                       : bf2f(((const unsigned short*)src)[i]);
}

// ---------------------------------------------------------------------------
// r16: ONE prep kernel replacing detect + convf + convertX + convertM.
// Each block self-computes the dtype flag from X's first 1KB.
// ---------------------------------------------------------------------------
__global__ __launch_bounds__(256) void k_prep(
    const void* __restrict__ X, const void* __restrict__ Mw,
    const void* __restrict__ Fil,
    unsigned short* __restrict__ Xbf, unsigned short* __restrict__ Mbf,
    float* __restrict__ Fw, int n4x, int n4m, int n4f)
{
    __shared__ int sflag;
    const int tid = threadIdx.x;
    if (tid < 64) {
        int cnt = 0;
        const unsigned int* Xu = (const unsigned int*)X;
#pragma unroll
        for (int i = 0; i < 4; ++i) {
            unsigned int wd = Xu[tid * 4 + i];
            cnt += (plaus16(wd >> 16) && plaus16(wd & 0xffffu)) ? 1 : 0;
        }
        for (int off = 32; off > 0; off >>= 1) cnt += __shfl_down(cnt, off);
        if (tid == 0) sflag = (cnt < 180) ? 1 : 0;
    }
    __syncthreads();
    const int isf32 = sflag;

    const int total = n4x + n4m + n4f;
    for (int i = blockIdx.x * 256 + tid; i < total; i += gridDim.x * 256) {
        if (i < n4x) {
            ushort4 o;
            if (isf32) {
                float4 v = ((const float4*)X)[i];
                o.x = f2bf(v.x); o.y = f2bf(v.y); o.z = f2bf(v.z); o.w = f2bf(v.w);
            } else {
                o = ((const ushort4*)X)[i];
            }
            ((ushort4*)Xbf)[i] = o;
        } else if (i < n4x + n4m) {
            const int j = i - n4x;
            ushort4 o;
            if (isf32) {
                float4 v = ((const float4*)Mw)[j];
                o.x = f2bf(v.x); o.y = f2bf(v.y); o.z = f2bf(v.z); o.w = f2bf(v.w);
            } else {
                o = ((const ushort4*)Mw)[j];
            }
            ((ushort4*)Mbf)[j] = o;
        } else {
            const int j = i - n4x - n4m;
            if (isf32) {
                ((float4*)Fw)[j] = ((const float4*)Fil)[j];
            } else {
                ushort4 u = ((const ushort4*)Fil)[j];
                ((float4*)Fw)[j] = make_float4(bf2f(u.x), bf2f(u.y),
                                               bf2f(u.z), bf2f(u.w));
            }
        }
    }
}

// ---------------------------------------------------------------------------
// FAST GEMM, fused chunk-sums. m97 pattern + XOR bank swizzle (r10) +
// r12 2-phase dbuf. Measured at the 2-phase structural ceiling (687 TF,
// r12/r14 pipelining A/B NULL; r16 XCD swizzle REGRESSED) — frozen.
// grid (rows/128, 4, NF), block 256.
// ---------------------------------------------------------------------------
__global__ __launch_bounds__(256, 3) void k_gemm_fast(
    const unsigned short* __restrict__ X,   // bf16 [B*T, DF]
    const unsigned short* __restrict__ Mw,  // bf16 [NF][DOUT][DF]
    const float* __restrict__ Fw,           // fp32 [TT][NF]
    unsigned short* __restrict__ Z,         // bf16 [rl][n][512]
    float* __restrict__ Cs,                 // fp32 [chunk][n][512]
    int r0)
{
    // union: dbuf {buf0: A[4096] B[4096] | buf1: A B} (16384 shorts) / sC (17408)
    __shared__ unsigned short sAB[128 * 136];
    __shared__ float sPhi[128];
    unsigned short* const sC = sAB;

    const int tid  = threadIdx.x;
    const int lane = tid & 63;
    const int w    = tid >> 6;
    const int wm   = w & 1, wn = w >> 1;
    const int tm   = blockIdx.x;
    const int on0  = blockIdx.y * 128;
    const int n    = blockIdx.z;

    const int rowg0 = r0 + tm * 128;
    if (tid < 128)
        sPhi[tid] = Fw[((rowg0 + tid) & (TT - 1)) * NF + n];

    const unsigned short* Ag = X + (size_t)rowg0 * DF;
    const unsigned short* Bg = Mw + (size_t)n * DOUT * DF + (size_t)on0 * DF;

    // Per-thread staging geometry (16B slots; XOR bank swizzle on source)
    auto stage = [&](int kt, int buf) {
        const unsigned short* Ak = Ag + kt * 32;
        const unsigned short* Bk = Bg + kt * 32;
        lds_u8* base = (lds_u8*)sAB + buf * 16384;
#pragma unroll
        for (int i = 0; i < 2; ++i) {
            const int cbase = i * 256 + w * 64;   // wave-uniform 16B-slot base
            const int c = cbase + lane;           // this lane's LDS slot
            const int r = c >> 2, qs = c & 3;
            const int qg = qs ^ ((r >> 1) & 3);   // swizzle: slot qs holds chunk qg
            __builtin_amdgcn_global_load_lds(
                (const glb_u8*)(Ak + (size_t)r * DF + qg * 8),
                base + cbase * 16, 16, 0, 0);
            __builtin_amdgcn_global_load_lds(
                (const glb_u8*)(Bk + (size_t)r * DF + qg * 8),
                base + 8192 + cbase * 16, 16, 0, 0);
        }
    };

    f32x4 acc[4][4];
#pragma unroll
    for (int i = 0; i < 4; i++)
#pragma unroll
        for (int j = 0; j < 4; j++) acc[i][j] = (f32x4){0.f, 0.f, 0.f, 0.f};

    stage(0, 0);
    __syncthreads();   // vmcnt(0) drain: buf0 ready

    const int lr = lane & 15;
    const int q  = lane >> 4;
    const int qsw = (q ^ ((lr >> 1) & 3)) * 8;    // (row>>1)&3 == (lr>>1)&3

    for (int kt = 0; kt < DF / 32; ++kt) {
        const int cur = kt & 1;
        if (kt < DF / 32 - 1) stage(kt + 1, cur ^ 1);   // loads in flight over compute

        const unsigned short* sAc = sAB + cur * 8192;
        const unsigned short* sBc = sAc + 4096;
        short8 a[4], b[4];
#pragma unroll
        for (int i = 0; i < 4; i++)
            a[i] = *(const short8*)&sAc[(wm * 64 + i * 16 + lr) * 32 + qsw];
#pragma unroll
        for (int j = 0; j < 4; j++)
            b[j] = *(const short8*)&sBc[(wn * 64 + j * 16 + lr) * 32 + qsw];
#pragma unroll
        for (int i = 0; i < 4; i++)
#pragma unroll
            for (int j = 0; j < 4; j++)
                acc[i][j] = __builtin_amdgcn_mfma_f32_16x16x32_bf16(
                    a[i], b[j], acc[i][j], 0, 0, 0);

        __syncthreads();   // drains this iter's stage + guards buf reuse
    }
    // last loop barrier passed: all ds_reads complete, sC may overlay dbuf

    // C/D layout (m89/m91-verified): col = lane&15, row = (lane>>4)*4 + reg
    const int rb = (lane >> 4) * 4;
#pragma unroll
    for (int i = 0; i < 4; i++)
#pragma unroll
        for (int j = 0; j < 4; j++)
#pragma unroll
            for (int r = 0; r < 4; r++) {
                int row = wm * 64 + i * 16 + rb + r;
                sC[row * 136 + wn * 64 + j * 16 + (lane & 15)] =
                    f2bf(acc[i][j][r] * sPhi[row]);
            }
    __syncthreads();

    // Z store (coalesced 16B)
#pragma unroll
    for (int it = 0; it < 8; ++it) {
        int row = it * 16 + (tid >> 4);
        int col = (tid & 15) * 8;
        uint4 v = *(const uint4*)&sC[row * 136 + col];
        *(uint4*)&Z[((size_t)(tm * 128 + row) * NF + n) * 512 + on0 + col] = v;
    }

    // Fused chunk sums: 16 chunks x 128 cols; thread -> (chunk ci, 8 cols).
    {
        const int ci  = tid >> 4;           // chunk within tile, 0..15
        const int col = (tid & 15) * 8;
        float s0=0.f,s1=0.f,s2=0.f,s3=0.f,s4=0.f,s5=0.f,s6=0.f,s7=0.f;
#pragma unroll
        for (int r = 0; r < CHF; ++r) {
            uint4 v = *(const uint4*)&sC[(ci * CHF + r) * 136 + col];
            s0 += lo16f(v.x); s1 += hi16f(v.x);
            s2 += lo16f(v.y); s3 += hi16f(v.y);
            s4 += lo16f(v.z); s5 += hi16f(v.z);
            s6 += lo16f(v.w); s7 += hi16f(v.w);
        }
        float* cp = &Cs[((size_t)(tm * 16 + ci) * NF + n) * 512 + on0 + col];
        *(float4*)cp       = make_float4(s0, s1, s2, s3);
        *(float4*)(cp + 4) = make_float4(s4, s5, s6, s7);
    }
}

// ---------------------------------------------------------------------------
// SLOW GEMM (fallback for tiny ws): register staging + in-flight convert.
// ---------------------------------------------------------------------------
__global__ __launch_bounds__(256, 2) void k_gemm(
    const void* __restrict__ Xv, const void* __restrict__ Mv,
    const void* __restrict__ Fv, const int* __restrict__ flag,
    unsigned short* __restrict__ Z, int r0, int o0, int W)
{
    __shared__ unsigned short sA[128 * 32];
    __shared__ unsigned short sB[128 * 32];
    __shared__ unsigned short sC[128 * 136];
    __shared__ float sPhi[128];

    const int isf32 = *flag;
    const int tid  = threadIdx.x;
    const int lane = tid & 63;
    const int w    = tid >> 6;
    const int wm   = w & 1, wn = w >> 1;
    const int tm   = blockIdx.x;
    const int on0  = o0 + blockIdx.y * 128;
    const int n    = blockIdx.z;

    const int rowg0 = r0 + tm * 128;
    if (tid < 128) {
        int t = (rowg0 + tid) & (TT - 1);
        sPhi[tid] = isf32 ? ((const float*)Fv)[t * NF + n]
                          : bf2f(((const unsigned short*)Fv)[t * NF + n]);
    }

    const unsigned short* Ah = (const unsigned short*)Xv + (size_t)rowg0 * DF;
    const unsigned short* Bh = (const unsigned short*)Mv +
        (size_t)n * DOUT * DF + (size_t)on0 * DF;
    const float* Af = (const float*)Xv + (size_t)rowg0 * DF;
    const float* Bf = (const float*)Mv + (size_t)n * DOUT * DF + (size_t)on0 * DF;

    f32x4 acc[4][4];
#pragma unroll
    for (int i = 0; i < 4; i++)
#pragma unroll
        for (int j = 0; j < 4; j++) acc[i][j] = (f32x4){0.f, 0.f, 0.f, 0.f};

    for (int kt = 0; kt < DF / 32; ++kt) {
        __syncthreads();
        if (!isf32) {
            const unsigned short* Ak = Ah + kt * 32;
            const unsigned short* Bk = Bh + kt * 32;
#pragma unroll
            for (int i = 0; i < 2; ++i) {
                const int c = i * 256 + tid;
                const int r = c >> 2, cc = (c & 3) * 8;
                *(short8*)&sA[r * 32 + cc] = *(const short8*)(Ak + (size_t)r * DF + cc);
                *(short8*)&sB[r * 32 + cc] = *(const short8*)(Bk + (size_t)r * DF + cc);
            }
        } else {
            const float* Ak = Af + kt * 32;
            const float* Bk = Bf + kt * 32;
#pragma unroll
            for (int i = 0; i < 2; ++i) {
                const int c = i * 256 + tid;
                const int r = c >> 2, cc = (c & 3) * 8;
                float4 a0 = *(const float4*)(Ak + (size_t)r * DF + cc);
                float4 a1 = *(const float4*)(Ak + (size_t)r * DF + cc + 4);
                float4 b0 = *(const float4*)(Bk + (size_t)r * DF + cc);
                float4 b1 = *(const float4*)(Bk + (size_t)r * DF + cc + 4);
                short8 sa, sb;
                sa[0]=(short)f2bf(a0.x); sa[1]=(short)f2bf(a0.y);
                sa[2]=(short)f2bf(a0.z); sa[3]=(short)f2bf(a0.w);
                sa[4]=(short)f2bf(a1.x); sa[5]=(short)f2bf(a1.y);
                sa[6]=(short)f2bf(a1.z); sa[7]=(short)f2bf(a1.w);
                sb[0]=(short)f2bf(b0.x); sb[1]=(short)f2bf(b0.y);
                sb[2]=(short)f2bf(b0.z); sb[3]=(short)f2bf(b0.w);
                sb[4]=(short)f2bf(b1.x); sb[5]=(short)f2bf(b1.y);
                sb[6]=(short)f2bf(b1.z); sb[7]=(short)f2bf(b1.w);
                *(short8*)&sA[r * 32 + cc] = sa;
                *(short8*)&sB[r * 32 + cc] = sb;
            }
        }
        __syncthreads();

        const int lr = lane & 15;
        const int lk = (lane >> 4) * 8;
        short8 a[4], b[4];
#pragma unroll
        for (int i = 0; i < 4; i++)
            a[i] = *(const short8*)&sA[(wm * 64 + i * 16 + lr) * 32 + lk];
#pragma unroll
        for (int j = 0; j < 4; j++)
            b[j] = *(const short8*)&sB[(wn * 64 + j * 16 + lr) * 32 + lk];
#pragma unroll
        for (int i = 0; i < 4; i++)
#pragma unroll
            for (int j = 0; j < 4; j++)
                acc[i][j] = __builtin_amdgcn_mfma_f32_16x16x32_bf16(
                    a[i], b[j], acc[i][j], 0, 0, 0);
    }

    const int rb = (lane >> 4) * 4;
#pragma unroll
    for (int i = 0; i < 4; i++)
#pragma unroll
        for (int j = 0; j < 4; j++)
#pragma unroll
            for (int r = 0; r < 4; r++) {
                int row = wm * 64 + i * 16 + rb + r;
                sC[row * 136 + wn * 64 + j * 16 + (lane & 15)] =
                    f2bf(acc[i][j][r] * sPhi[row]);
            }
    __syncthreads();
#pragma unroll
    for (int it = 0; it < 8; ++it) {
        int row = it * 16 + (tid >> 4);
        int col = (tid & 15) * 8;
        uint4 v = *(const uint4*)&sC[row * 136 + col];
        *(uint4*)&Z[((size_t)(tm * 128 + row) * NF + n) * W + (on0 - o0) + col] = v;
    }
}

// ---------------------------------------------------------------------------
// Kernel 2a (slow tier only): chunk sums. grid (nch, NF), block W/2.
// ---------------------------------------------------------------------------
__global__ __launch_bounds__(256, 2) void k_csum(
    const unsigned short* __restrict__ Z, float* __restrict__ Cs,
    int W, int CHs)
{
    const int c = blockIdx.x, n = blockIdx.y, tid = threadIdx.x;
    const unsigned short* p = Z + ((size_t)(c * CHs) * NF + n) * W + tid * 2;
    float sx = 0.f, sy = 0.f;
#pragma unroll 8
    for (int t = 0; t < CHs; ++t) {
        unsigned int u = *(const unsigned int*)(p + (size_t)t * NF * W);
        sx += lo16f(u);
        sy += hi16f(u);
    }
    float2* q = (float2*)&Cs[((size_t)c * NF + n) * W + tid * 2];
    *q = make_float2(sx, sy);
}

// ---------------------------------------------------------------------------
// Kernel 2b: exclusive prefix over chunks (+ cross-pass carry Gc, nbat==1).
// r17 cooperative form: 4 waves split chunk range in quarters (P1 sum,
// P2 LDS exchange, P3 exclusive walk w/ 8-deep prefetch). Serial depth /4.
// grid = nbat*NF*(W/128) blocks of 256.
// ---------------------------------------------------------------------------
__global__ __launch_bounds__(256, 4) void k_prefix(
    float* __restrict__ Cs, float* __restrict__ Gc,
    int W, int rr, int nch, int nbat)
{
    __shared__ float2 sPart[4][64];
    const int tid  = threadIdx.x;
    const int wv   = tid >> 6, lane = tid & 63;
    const int obw  = W >> 7;                 // col-blocks of 128
    const int perB = NF * obw;
    const int gw   = blockIdx.x;
    const int b    = gw / perB;
    const int rest = gw % perB;
    const int n    = rest / obw;
    const int ob   = rest % obw;
    const int opair = ob * 64 + lane;

    float* base = Cs + (size_t)b * nch * NF * W + (size_t)n * W + opair * 2;
    const size_t cstride = (size_t)NF * W;   // floats between chunks
    const int Q  = nch >> 2;                 // nch is pow2 >= 4 in all tiers
    const int c0 = wv * Q;
    const int end = c0 + Q;

    // P1: wave-local sum of own quarter (independent loads, MLP-friendly)
    float sx = 0.f, sy = 0.f;
    for (int c = c0; c < end; ++c) {
        float2 v = *(const float2*)(base + (size_t)c * cstride);
        sx += v.x; sy += v.y;
    }
    sPart[wv][lane] = make_float2(sx, sy);
    __syncthreads();

    // P2: carry = Gc (cross-pass) + lower quarters
    float cx = 0.f, cy = 0.f;
    if (nbat == 1 && rr != 0) {
        float2 gv = *(const float2*)&Gc[(size_t)n * DOUT + opair * 2];
        cx = gv.x; cy = gv.y;
    }
    for (int w2 = 0; w2 < wv; ++w2) {
        float2 p = sPart[w2][lane];
        cx += p.x; cy += p.y;
    }

    // P3: exclusive walk over own quarter (8-deep prefetch when Q>=16)
    int c = c0;
    if (Q >= 16) {
        float2 v[8], nx[8];
#pragma unroll
        for (int k = 0; k < 8; ++k)
            v[k] = *(float2*)(base + (size_t)(c + k) * cstride);
        for (; c + 16 <= end; c += 8) {
#pragma unroll
            for (int k = 0; k < 8; ++k)
                nx[k] = *(float2*)(base + (size_t)(c + 8 + k) * cstride);
#pragma unroll
            for (int k = 0; k < 8; ++k) {
                float2* p = (float2*)(base + (size_t)(c + k) * cstride);
                float2 t = v[k];
                *p = make_float2(cx, cy);
                cx += t.x; cy += t.y;
                v[k] = nx[k];
            }
        }
#pragma unroll
        for (int k = 0; k < 8; ++k) {
            float2* p = (float2*)(base + (size_t)(c + k) * cstride);
            float2 t = v[k];
            *p = make_float2(cx, cy);
            cx += t.x; cy += t.y;
        }
        c += 8;
    }
    for (; c < end; ++c) {
        float2* p = (float2*)(base + (size_t)c * cstride);
        float2 t = *p;
        *p = make_float2(cx, cy);
        cx += t.x; cy += t.y;
    }

    // top wave's final carry = inclusive grand total for this pass
    if (nbat == 1 && wv == 3)
        *(float2*)&Gc[(size_t)n * DOUT + opair * 2] = make_float2(cx, cy);
}

// ---------------------------------------------------------------------------
// Kernel 2c FAST (W=512, CHs=CHF=8): LDS-staged scan.
// r18: r17's TLP-doubling was NULL — scan is issue/latency-bound on its 48
// strided 8B loads/thread (256B/wave-instr at 24KB stride), not wave-starved.
// A block (cg,y) consumes exactly a 48KB slab of Z (8 rows x 24 filt x 128
// cols). Stage it via global_load_lds: 12 rounds x 256 thr x 16B, fully
// coalesced (4KB/wave-instr), linear LDS dest (wave-uniform base+lane*16).
// t-loop then reads LDS (lanes stride 4B -> 2/bank = free). Per-thread
// global loads 48 scattered -> 12 coalesced. LDS 48+16+0.75 = 67KB -> 2
// blocks/CU; neighbor block's compute covers this block's DMA.
// Accumulation order per thread IDENTICAL to r17 -> bit-identical output.
// grid (nch_total, 4), block 256.
// ---------------------------------------------------------------------------
#define JLIST(F) F(0) F(1) F(2) F(3) F(4) F(5)

__global__ __launch_bounds__(256, 2) void k_scan8(
    const unsigned short* __restrict__ Z, const float* __restrict__ Cs,
    const float* __restrict__ Fw, float* __restrict__ Out,
    int r0)
{
    __shared__ unsigned short sZ[CHF * NF * 128];   // 48 KB
    __shared__ float sPhi[CHF * NF];                // 768 B
    __shared__ float2 sP[4][CHF][64];               // 16 KB
    const int cg = blockIdx.x, tid = threadIdx.x;
    const int g = tid >> 6, op = tid & 63;
    const int ng0 = g * 6;
    const int y  = blockIdx.y;                      // col-block of 128
    const int t0g = r0 + cg * CHF;
    const int t0 = t0g & (TT - 1);

    // Stage the Z slab: segment s = row*NF + n (192 segs x 256B each).
    // global: Z[(cg*8*NF + s)*512 + y*128 ..+128); LDS: sZ + s*256B.
    {
        const glb_u8* src = (const glb_u8*)(Z + (size_t)cg * CHF * NF * 512 + y * 128);
        lds_u8* dst = (lds_u8*)sZ;
        const int soff = (tid >> 4) * 1024 + (tid & 15) * 16;  // seg*1024B + within
#pragma unroll
        for (int rr2 = 0; rr2 < 12; ++rr2) {
            __builtin_amdgcn_global_load_lds(
                src + (size_t)rr2 * 16384 + soff,
                dst + rr2 * 4096 + tid * 16, 16, 0, 0);
        }
    }
    if (tid < CHF * NF)
        sPhi[tid] = Fw[(t0 + tid / NF) * NF + (tid % NF)];
    __syncthreads();   // drains DMA + sPhi visible

#define DECLG(j) float gx##j, gy##j;
    JLIST(DECLG)
#define INITG(j) { float2 v = *(const float2*)&Cs[((size_t)cg * NF + ng0 + j) * 512 + (y * 64 + op) * 2]; \
                   gx##j = v.x; gy##j = v.y; }
    JLIST(INITG)

    float* outb = Out + (size_t)t0g * DOUT + y * 128 + op * 2;
#pragma unroll
    for (int tt = 0; tt < CHF; ++tt) {
        float ax = 0.f, ay = 0.f;
        const float* php = &sPhi[tt * NF + ng0];
#define UPDG(j) { unsigned int u = *(const unsigned int*)&sZ[(tt * NF + ng0 + j) * 128 + op * 2]; \
                  gx##j += lo16f(u); gy##j += hi16f(u); \
                  float ph = php[j]; ax += ph * gx##j; ay += ph * gy##j; }
        JLIST(UPDG)
        sP[g][tt][op] = make_float2(ax, ay);
    }
    __syncthreads();
#pragma unroll
    for (int k = 0; k < 2; ++k) {
        const int tt = g * 2 + k;
        float2 p0 = sP[0][tt][op], p1 = sP[1][tt][op],
               p2 = sP[2][tt][op], p3 = sP[3][tt][op];
        *(float2*)(outb + (size_t)tt * DOUT) =
            make_float2(p0.x + p1.x + p2.x + p3.x,
                        p0.y + p1.y + p2.y + p3.y);
    }
}

// ---------------------------------------------------------------------------
// Kernel 2c GENERIC (slow tier: any W, CHs=32). r17 form.
// grid (nch_total, W/128), block 256.
// ---------------------------------------------------------------------------
__global__ __launch_bounds__(256, 8) void k_scan(
    const unsigned short* __restrict__ Z, const float* __restrict__ Cs,
    const float* __restrict__ Fw, float* __restrict__ Out,
    int r0, int o0, int W, int CHs)
{
    __shared__ float sPhi[32 * NF];
    __shared__ float2 sP[4][8][64];
    const int cg = blockIdx.x, tid = threadIdx.x;
    const int g = tid >> 6, op = tid & 63;
    const int ng0 = g * 6;
    const int c2  = (blockIdx.y * 64 + op) * 2;     // 2 cols per thread
    const int act = (c2 + 2 <= W);
    const int c2u = act ? c2 : (W - 2);             // clamped (harmless reads)
    const int t0g = r0 + cg * CHs;
    const int t0 = t0g & (TT - 1);
    for (int i = tid; i < CHs * NF; i += 256)
        sPhi[i] = Fw[(t0 + i / NF) * NF + (i % NF)];
    __syncthreads();

    JLIST(DECLG)
#define INITG2(j) { float2 v = *(const float2*)&Cs[((size_t)cg * NF + ng0 + j) * W + c2u]; \
                    gx##j = v.x; gy##j = v.y; }
    JLIST(INITG2)

    const unsigned short* zp = Z + ((size_t)cg * CHs * NF + ng0) * W + c2u;
    float* outb = Out + (size_t)t0g * DOUT + o0 + c2;
    for (int tb = 0; tb < CHs; tb += 8) {
#pragma unroll
        for (int tt = 0; tt < 8; ++tt) {
            float ax = 0.f, ay = 0.f;
            const float* php = &sPhi[(tb + tt) * NF + ng0];
#define UPDG2(j) { unsigned int u = *(const unsigned int*)(zp + (size_t)j * W); \
                   gx##j += lo16f(u); gy##j += hi16f(u); \
                   float ph = php[j]; ax += ph * gx##j; ay += ph * gy##j; }
            JLIST(UPDG2)
            sP[g][tt][op] = make_float2(ax, ay);
            zp += (size_t)NF * W;
        }
        __syncthreads();
#pragma unroll
        for (int k = 0; k < 2; ++k) {
            const int tt = g * 2 + k;
            float2 p0 = sP[0][tt][op], p1 = sP[1][tt][op],
                   p2 = sP[2][tt][op], p3 = sP[3][tt][op];
            if (act)
                *(float2*)(outb + (size_t)(tb + tt) * DOUT) =
                    make_float2(p0.x + p1.x + p2.x + p3.x,
                                p0.y + p1.y + p2.y + p3.y);
        }
        __syncthreads();
    }
}

// ---------------------------------------------------------------------------
extern "C" void kernel_launch(void* const* d_in, const int* in_sizes, int n_in,
                              void* d_out, int out_size, void* d_ws, size_t ws_size,
                              hipStream_t stream)
{
    const void* X = d_in[0]; const void* Fil = d_in[1]; const void* Mw = d_in[2];
    for (int i = 0; i < n_in && i < 3; ++i) {
        if (in_sizes[i] == BQ * TT * DF)        X   = d_in[i];
        else if (in_sizes[i] == TT * NF)        Fil = d_in[i];
        else if (in_sizes[i] == NF * DOUT * DF) Mw  = d_in[i];
    }
    float* Out = (float*)d_out;

    const size_t offF = 256;
    const size_t nbF  = (size_t)TT * NF * 4;
    const size_t off0 = offF + nbF;
    const size_t nbX  = (size_t)BQ * TT * DF * 2;    // 8.39 MB
    const size_t nbM  = (size_t)NF * DOUT * DF * 2;  // 12.58 MB
    const size_t nbGc = (size_t)NF * DOUT * 4;

    int* flag = (int*)d_ws;
    float* Fw = (float*)((char*)d_ws + offF);

    const int n4x = BQ * TT * DF / 4;
    const int n4m = NF * DOUT * DF / 4;
    const int n4f = TT * NF / 4;

    // ---- Multi-batch tiers: G batches per pass (G=4: Z 201 MB + Cs 50 MB;
    //      G=2: Z 101 MB + Cs 25 MB). Falls through to per-batch tier. ----
    for (int G = BQ; G >= 2; G >>= 1) {
        const size_t zB  = (size_t)G * TT * NF * 512 * 2;
        const size_t csB = (size_t)(G * TT / CHF) * NF * 512 * 4;
        if (off0 + nbX + nbM + zB + csB > ws_size) continue;

        unsigned short* Xbf = (unsigned short*)((char*)d_ws + off0);
        unsigned short* Mbf = (unsigned short*)((char*)Xbf + nbX);
        unsigned short* Z   = (unsigned short*)((char*)Mbf + nbM);
        float* Cs = (float*)((char*)Z + zB);

        hipLaunchKernelGGL(k_prep, dim3(2048), dim3(256), 0, stream,
                           X, Mw, Fil, Xbf, Mbf, Fw, n4x, n4m, n4f);

        const int nch = TT / CHF;            // per batch: 256
        for (int b0 = 0; b0 < BQ; b0 += G) {
            hipLaunchKernelGGL(k_gemm_fast, dim3(G * TT / 128, 4, NF), dim3(256),
                               0, stream, Xbf, Mbf, Fw, Z, Cs, b0 * TT);
            hipLaunchKernelGGL(k_prefix, dim3(G * NF * 4), dim3(256),
                               0, stream, Cs, (float*)nullptr, 512, 0, nch, G);
            hipLaunchKernelGGL(k_scan8, dim3(G * nch, 4), dim3(256), 0, stream,
                               Z, Cs, Fw, Out, b0 * TT);
        }
        return;
    }

    // ---- Per-batch fused tier (proven >= 84 MB fits RT=2048) ----
    {
        static const int rts[5] = {2048, 1024, 512, 256, 128};
        int RT = 0;
        for (int ri = 0; ri < 5; ++ri) {
            size_t need = off0 + nbX + nbM
                        + (size_t)rts[ri] * NF * 512 * 2
                        + (size_t)(rts[ri] / CHF) * NF * 512 * 4 + nbGc;
            if (need <= ws_size) { RT = rts[ri]; break; }
        }
        if (RT > 0) {
            unsigned short* Xbf = (unsigned short*)((char*)d_ws + off0);
            unsigned short* Mbf = (unsigned short*)((char*)Xbf + nbX);
            unsigned short* Z   = (unsigned short*)((char*)Mbf + nbM);
            float* Cs = (float*)((char*)Z + (size_t)RT * NF * 512 * 2);
            float* Gc = (float*)((char*)Cs + (size_t)(RT / CHF) * NF * 512 * 4);

            hipLaunchKernelGGL(k_prep, dim3(2048), dim3(256), 0, stream,
                               X, Mw, Fil, Xbf, Mbf, Fw, n4x, n4m, n4f);

            const int nrr = TT / RT, nch = RT / CHF;
            for (int b = 0; b < BQ; ++b) {
                for (int rr = 0; rr < nrr; ++rr) {
                    const int r0 = b * TT + rr * RT;
                    hipLaunchKernelGGL(k_gemm_fast, dim3(RT / 128, 4, NF), dim3(256),
                                       0, stream, Xbf, Mbf, Fw, Z, Cs, r0);
                    hipLaunchKernelGGL(k_prefix, dim3(NF * 4), dim3(256),
                                       0, stream, Cs, Gc, 512, rr, nch, 1);
                    hipLaunchKernelGGL(k_scan8, dim3(nch, 4), dim3(256), 0, stream,
                                       Z, Cs, Fw, Out, r0);
                }
            }
            return;
        }
    }

    // ---- Slow tiers (tiny ws): in-kernel convert GEMM, o-sliced, CH=32 ----
    hipLaunchKernelGGL(k_detect, dim3(1), dim3(64), 0, stream,
                       (const unsigned int*)X, flag);
    hipLaunchKernelGGL(k_convf, dim3(192), dim3(256), 0, stream,
                       Fil, Fw, flag, TT * NF);

    static const int cRT[7] = {2048, 1024, 512, 256, 128, 128, 128};
    static const int cW[7]  = {512, 512, 512, 512, 512, 256, 128};
    int RTs = 128, W = 128;
    for (int ci = 0; ci < 7; ++ci) {
        size_t need = off0 + (size_t)cRT[ci] * NF * cW[ci] * 2
                    + (size_t)(cRT[ci] / 32) * NF * cW[ci] * 4 + nbGc;
        if (need <= ws_size) { RTs = cRT[ci]; W = cW[ci]; break; }
    }
    unsigned short* Z = (unsigned short*)((char*)d_ws + off0);
    float* Cs = (float*)((char*)Z + (size_t)RTs * NF * W * 2);
    float* Gc = (float*)((char*)Cs + (size_t)(RTs / 32) * NF * W * 4);

    const int nrr = TT / RTs, nch = RTs / 32;
    for (int b = 0; b < BQ; ++b) {
        for (int o0 = 0; o0 < DOUT; o0 += W) {
            for (int rr = 0; rr < nrr; ++rr) {
                const int r0 = b * TT + rr * RTs;
                hipLaunchKernelGGL(k_gemm, dim3(RTs / 128, W / 128, NF), dim3(256),
                                   0, stream, X, Mw, Fil, flag, Z, r0, o0, W);
                hipLaunchKernelGGL(k_csum, dim3(nch, NF), dim3(W / 2), 0, stream,
                                   Z, Cs, W, 32);
                hipLaunchKernelGGL(k_prefix, dim3(NF * (W / 128)), dim3(256),
                                   0, stream, Cs, Gc, W, rr, nch, 1);
                hipLaunchKernelGGL(k_scan, dim3(nch, W / 128), dim3(256),
                                   0, stream, Z, Cs, Fw, Out, r0, o0, W, 32);
            }
        }
    }
}